// Round 18
// baseline (72.329 us; speedup 1.0000x reference)
//
#include <hip/hip_runtime.h>

// GATv2 layer, N=1024 nodes, C=256 channels. Flash-fused, dtype-adaptive.
// v15 = r15 base (best total, 60.45us) with the fused kernel rebuilt
// BARRIER-FREE: gt is read directly from global (512KB -> L2-resident,
// L1-assisted within a block) instead of LDS staging. No __syncthreads in
// the main loop; waves free-run with deep vmcnt queues. LDS holds only the
// a-vector and a packed per-wave float2 p-buffer (both rows' p in one b64).
// lin (16-row tiles), sdot, combine(ns==8 fast path) = r15 verbatim.
//
// ws layout (bytes):
//   [0,   512K)    gsh  g_src as f16 [1024][256]
//   [512K, 1M)     gth  g_tgt as f16 [1024][256]
//   [1M,  1M+4K)   sgt06: 0.6 * dot(a, g_tgt[j]) per j, f32
//   [+,  +NS*1M)   po   partial O f32 [NS][1024][256]
//   next NS*4K     pm   partial max per (z,row)  (always 0)
//   next NS*4K     pls  partial denom per (z,row)

typedef unsigned short u16;
typedef unsigned int   u32;
typedef _Float16 h2 __attribute__((ext_vector_type(2)));

#define NNODE 1024
#define NC    256
#define NEG   0.2f

__device__ __forceinline__ float bf2f(u16 h) {
    u32 u = ((u32)h) << 16;
    return __builtin_bit_cast(float, u);
}
__device__ __forceinline__ u16 f2bf(float f) {
    u32 u = __builtin_bit_cast(u32, f);
    u32 r = (u + 0x7FFFu + ((u >> 16) & 1u)) >> 16;   // RNE
    return (u16)r;
}
__device__ __forceinline__ u16 f2h(float f) {
    _Float16 h = (_Float16)f;                         // RNE
    return __builtin_bit_cast(u16, h);
}
__device__ __forceinline__ h2 bch(u32 u) { return __builtin_bit_cast(h2, u); }
__device__ __forceinline__ h2 habs2(h2 y) {           // |y| packed: 1 v_and
    u32 u = __builtin_bit_cast(u32, y) & 0x7FFF7FFFu;
    return __builtin_bit_cast(h2, u);
}
__device__ __forceinline__ float dot2(h2 a, h2 b, float acc) {
#if __has_builtin(__builtin_amdgcn_fdot2)
    return __builtin_amdgcn_fdot2(a, b, acc, false);
#else
    acc = fmaf((float)a.x, (float)b.x, acc);
    return fmaf((float)a.y, (float)b.y, acc);
#endif
}

// per-wave dtype probe (uniform; verified rounds 2..17).
__device__ __forceinline__ int wave_detect(const u16* __restrict__ nodes, int lane)
{
    ushort4 v = *(const ushort4*)(nodes + lane * 4);
    const u16 h[4] = {v.x, v.y, v.z, v.w};
    int cnt = 0;
    #pragma unroll
    for (int q = 0; q < 4; ++q) {
        int e = (h[q] >> 7) & 0xFF;
        cnt += (e >= 132 || (e >= 1 && e <= 90)) ? 1 : 0;
    }
    #pragma unroll
    for (int off = 32; off; off >>= 1) cnt += __shfl_xor(cnt, off, 64);
    return (cnt >= 64) ? 0 : 1;
}

// ---------------------------------------------------------------------------
// K1: g = nodes @ W^T + b, output packed f16 (gsh / gth). r15/16-verified.
// 16-row i-tiles, grid (8, 64) = 512 blocks, 256 threads.
// ---------------------------------------------------------------------------
__global__ __launch_bounds__(256) void lin_kernel(
    const void* __restrict__ nodes_v,
    const void* __restrict__ Wsrc_v, const void* __restrict__ bsrc_v,
    const void* __restrict__ Wtgt_v, const void* __restrict__ btgt_v,
    u16* __restrict__ gsh, u16* __restrict__ gth)
{
    __shared__ float nT[64][17];   // [k][i], 16 rows
    __shared__ float wT[64][68];   // [k][c]

    const int t  = threadIdx.x;
    const int bf = wave_detect((const u16*)nodes_v, t & 63);
    const int ct = blockIdx.x;
    const int it = blockIdx.y;
    const int i0 = it * 16;
    const bool is_src = (ct < 4);
    const int c0 = (is_src ? ct : ct - 4) * 64;
    const void* __restrict__ Wv = is_src ? Wsrc_v : Wtgt_v;
    const void* __restrict__ bv = is_src ? bsrc_v : btgt_v;
    u16* __restrict__ g         = is_src ? gsh : gth;

    const int tc = t & 15, ti = t >> 4;
    float acc[4] = {};

    for (int k0 = 0; k0 < NC; k0 += 64) {
        __syncthreads();
        {   // stage nodes tile [16 i][64 k] -> nT[k][i]
            int kg = t & 15, ii = t >> 4;
            float vals[4];
            if (bf) {
                ushort4 v = *(const ushort4*)((const u16*)nodes_v + (i0 + ii) * NC + k0 + kg * 4);
                vals[0] = bf2f(v.x); vals[1] = bf2f(v.y);
                vals[2] = bf2f(v.z); vals[3] = bf2f(v.w);
            } else {
                const float* nf = (const float*)nodes_v;
                float4 v = *(const float4*)(nf + (i0 + ii) * NC + k0 + kg * 4);
                vals[0] = v.x; vals[1] = v.y; vals[2] = v.z; vals[3] = v.w;
            }
            #pragma unroll
            for (int q = 0; q < 4; ++q) nT[kg * 4 + q][ii] = vals[q];
        }
        {   // stage W tile [64 c][64 k] -> wT[k][c]
            int cc = t & 63, kg = t >> 6;
            float vals[16];
            if (bf) {
                const u16* W = (const u16*)Wv;
                uint4 v0 = *(const uint4*)(W + (c0 + cc) * NC + k0 + kg * 16);
                uint4 v1 = *(const uint4*)(W + (c0 + cc) * NC + k0 + kg * 16 + 8);
                const u16* p0 = (const u16*)&v0;
                const u16* p1 = (const u16*)&v1;
                #pragma unroll
                for (int q = 0; q < 8; ++q) { vals[q] = bf2f(p0[q]); vals[8 + q] = bf2f(p1[q]); }
            } else {
                const float* W = (const float*)Wv;
                #pragma unroll
                for (int h = 0; h < 4; ++h) {
                    float4 v = *(const float4*)(W + (c0 + cc) * NC + k0 + kg * 16 + 4 * h);
                    vals[4 * h + 0] = v.x; vals[4 * h + 1] = v.y;
                    vals[4 * h + 2] = v.z; vals[4 * h + 3] = v.w;
                }
            }
            #pragma unroll
            for (int q = 0; q < 16; ++q) wT[kg * 16 + q][cc] = vals[q];
        }
        __syncthreads();
        #pragma unroll 8
        for (int kk = 0; kk < 64; ++kk) {
            float  a  = nT[kk][ti];
            float4 bv4 = *(const float4*)&wT[kk][4 * tc];
            acc[0] = fmaf(a, bv4.x, acc[0]);
            acc[1] = fmaf(a, bv4.y, acc[1]);
            acc[2] = fmaf(a, bv4.z, acc[2]);
            acc[3] = fmaf(a, bv4.w, acc[3]);
        }
    }

    float bb[4];
    #pragma unroll
    for (int q = 0; q < 4; ++q)
        bb[q] = bf ? bf2f(((const u16*)bv)[c0 + 4 * tc + q])
                   : ((const float*)bv)[c0 + 4 * tc + q];
    const int irow = i0 + ti;
    ushort4 ov;
    ov.x = f2h(acc[0] + bb[0]);
    ov.y = f2h(acc[1] + bb[1]);
    ov.z = f2h(acc[2] + bb[2]);
    ov.w = f2h(acc[3] + bb[3]);
    *(ushort4*)(g + (size_t)irow * NC + c0 + 4 * tc) = ov;
}

// ---------------------------------------------------------------------------
// K1b: sgt06[j] = 0.6 * sum_c a_c * g_tgt[j][c]  (verified round 8).
// grid 256 x 256; wave = row.
// ---------------------------------------------------------------------------
__global__ __launch_bounds__(256) void sdot_kernel(
    const u16* __restrict__ gth, const void* __restrict__ aw_v,
    const u16* __restrict__ nodes_u16, float* __restrict__ sgt06)
{
    const int t    = threadIdx.x;
    const int lane = t & 63;
    const int bf   = wave_detect(nodes_u16, lane);
    const int row  = blockIdx.x * 4 + (t >> 6);

    float a0, a1, a2, a3;
    if (bf) {
        ushort4 a4 = *(const ushort4*)((const u16*)aw_v + lane * 4);
        a0 = bf2f(a4.x); a1 = bf2f(a4.y); a2 = bf2f(a4.z); a3 = bf2f(a4.w);
    } else {
        float4 a4 = *(const float4*)((const float*)aw_v + lane * 4);
        a0 = a4.x; a1 = a4.y; a2 = a4.z; a3 = a4.w;
    }
    ushort4 gv = *(const ushort4*)(gth + (size_t)row * NC + lane * 4);
    float s = a0 * (float)__builtin_bit_cast(_Float16, gv.x)
            + a1 * (float)__builtin_bit_cast(_Float16, gv.y)
            + a2 * (float)__builtin_bit_cast(_Float16, gv.z)
            + a3 * (float)__builtin_bit_cast(_Float16, gv.w);
    #pragma unroll
    for (int off = 32; off; off >>= 1) s += __shfl_xor(s, off, 64);
    if (lane == 0) sgt06[row] = 0.6f * s;
}

// ---------------------------------------------------------------------------
// K2: fused score + softmax (no max-subtraction) + PV — BARRIER-FREE.
// 512 threads, 8 waves, 2 rows/wave. gt read directly from global (L2/L1
// resident); LDS holds only a32 and packed per-wave p2. One barrier total
// (after a32 staging). Waves free-run across j tiles.
// ---------------------------------------------------------------------------
__global__ __launch_bounds__(512, 2) void fused_kernel(
    const u16* __restrict__ gsh, const u16* __restrict__ gth,
    const void* __restrict__ aw_v, const int* __restrict__ adj,
    const u16* __restrict__ nodes_u16, const float* __restrict__ sgt06,
    int jcnt, float* __restrict__ po, float* __restrict__ pm,
    float* __restrict__ pls, void* __restrict__ out_v)
{
    __shared__ u32    a32[128];       // 0.4*a as f16x2
    __shared__ float2 p2[8][64];      // per-wave packed (p_row0, p_row1)

    const int t    = threadIdx.x;
    const int i    = t >> 6;          // wave id 0..7; rows 2i, 2i+1
    const int lane = t & 63;
    const int bf   = wave_detect(nodes_u16, lane);
    const int r0   = blockIdx.x * 16 + 2 * i;
    const int z    = blockIdx.y;
    const int jbase = z * jcnt;
    const int jl = lane & 15, q  = lane >> 4;   // score layout
    const int oc = lane & 31, hh = lane >> 5;   // PV layout

    if (t < 128) {                    // stage 0.4*a as f16x2 (flag-converted)
        float a0, a1;
        if (bf) { a0 = bf2f(((const u16*)aw_v)[2 * t]); a1 = bf2f(((const u16*)aw_v)[2 * t + 1]); }
        else    { a0 = ((const float*)aw_v)[2 * t];     a1 = ((const float*)aw_v)[2 * t + 1]; }
        h2 av; av.x = (_Float16)(0.4f * a0); av.y = (_Float16)(0.4f * a1);
        a32[t] = __builtin_bit_cast(u32, av);
    }

    // both rows' g_src quarter (64 ch each) into registers: 2 x 32 x h2
    u32 gsr[2][32];
    #pragma unroll
    for (int r = 0; r < 2; ++r) {
        const u16* src = gsh + (size_t)(r0 + r) * NC + q * 64;
        #pragma unroll
        for (int k = 0; k < 8; ++k) {
            uint4 gv = *(const uint4*)(src + 8 * k);
            gsr[r][4 * k + 0] = gv.x; gsr[r][4 * k + 1] = gv.y;
            gsr[r][4 * k + 2] = gv.z; gsr[r][4 * k + 3] = gv.w;
        }
    }
    __syncthreads();                  // a32 visible (the ONLY block barrier)

    // Sgs06[r] = 1.5 * dot(0.4a, gsr[r]) reduced over the wave
    float Sgs06[2];
    #pragma unroll
    for (int r = 0; r < 2; ++r) {
        float sg = 0.f;
        #pragma unroll
        for (int k = 0; k < 8; ++k) {
            uint4 a4 = *(const uint4*)&a32[q * 32 + 4 * k];
            sg = dot2(bch(a4.x), bch(gsr[r][4 * k + 0]), sg);
            sg = dot2(bch(a4.y), bch(gsr[r][4 * k + 1]), sg);
            sg = dot2(bch(a4.z), bch(gsr[r][4 * k + 2]), sg);
            sg = dot2(bch(a4.w), bch(gsr[r][4 * k + 3]), sg);
        }
        sg += __shfl_xor(sg, 16, 64);
        sg += __shfl_xor(sg, 32, 64);
        Sgs06[r] = 1.5f * sg;
    }

    float l[2] = {0.f, 0.f};          // per-lane partial sums
    float of[2][8] = {};              // [row][ch 8*oc..8*oc+7] (j-parity hh)

    for (int j0 = jbase; j0 < jbase + jcnt; j0 += 64) {
        const float sgtj = sgt06[j0 + lane];

        // ---- score abs-part: gt read straight from global (L2/L1) ----
        float spv[2][4] = {};
        #pragma unroll
        for (int k = 0; k < 8; ++k) {
            uint4 a4 = *(const uint4*)&a32[q * 32 + 4 * k];
            h2 a0 = bch(a4.x), a1 = bch(a4.y), a2 = bch(a4.z), a3 = bch(a4.w);
            #pragma unroll
            for (int p = 0; p < 4; ++p) {
                const int rowp = 16 * p + jl;
                uint4 g4 = *(const uint4*)(gth + (size_t)(j0 + rowp) * NC + (q * 8 + k) * 8);
                h2 t0 = bch(g4.x), t1 = bch(g4.y), t2v = bch(g4.z), t3 = bch(g4.w);
                #pragma unroll
                for (int r = 0; r < 2; ++r) {
                    spv[r][p] = dot2(a0, habs2(bch(gsr[r][4 * k + 0]) + t0), spv[r][p]);
                    spv[r][p] = dot2(a1, habs2(bch(gsr[r][4 * k + 1]) + t1), spv[r][p]);
                    spv[r][p] = dot2(a2, habs2(bch(gsr[r][4 * k + 2]) + t2v), spv[r][p]);
                    spv[r][p] = dot2(a3, habs2(bch(gsr[r][4 * k + 3]) + t3), spv[r][p]);
                }
            }
        }
        #pragma unroll
        for (int r = 0; r < 2; ++r)
            #pragma unroll
            for (int p = 0; p < 4; ++p) {   // reduce over q (lane bits 4,5)
                spv[r][p] += __shfl_xor(spv[r][p], 16, 64);
                spv[r][p] += __shfl_xor(spv[r][p], 32, 64);
            }

        // ---- p = exp(s) directly (verified r13); l per-lane ----
        float pr[2];
        #pragma unroll
        for (int r = 0; r < 2; ++r) {
            const float sabs = (lane < 16) ? spv[r][0] : (lane < 32) ? spv[r][1]
                             : (lane < 48) ? spv[r][2] : spv[r][3];
            const float s = sabs + Sgs06[r] + sgtj;
            const int valid = adj[(size_t)(r0 + r) * NNODE + j0 + lane];
            pr[r] = valid ? __expf(s) : 0.f;
            l[r] += pr[r];
        }
        p2[i][lane] = make_float2(pr[0], pr[1]);   // wave-local, one b64

        // ---- PV: per 2 j one global b128 (8 ch) + one packed p read ----
        #pragma unroll 4
        for (int jp = 0; jp < 32; ++jp) {
            const int j = 2 * jp + hh;
            const float2 w = p2[i][j];
            uint4 g4 = *(const uint4*)(gth + (size_t)(j0 + j) * NC + oc * 8);
            h2 v0 = bch(g4.x), v1 = bch(g4.y), v2 = bch(g4.z), v3 = bch(g4.w);
            of[0][0] = fmaf(w.x, (float)v0.x, of[0][0]);
            of[0][1] = fmaf(w.x, (float)v0.y, of[0][1]);
            of[0][2] = fmaf(w.x, (float)v1.x, of[0][2]);
            of[0][3] = fmaf(w.x, (float)v1.y, of[0][3]);
            of[0][4] = fmaf(w.x, (float)v2.x, of[0][4]);
            of[0][5] = fmaf(w.x, (float)v2.y, of[0][5]);
            of[0][6] = fmaf(w.x, (float)v3.x, of[0][6]);
            of[0][7] = fmaf(w.x, (float)v3.y, of[0][7]);
            of[1][0] = fmaf(w.y, (float)v0.x, of[1][0]);
            of[1][1] = fmaf(w.y, (float)v0.y, of[1][1]);
            of[1][2] = fmaf(w.y, (float)v1.x, of[1][2]);
            of[1][3] = fmaf(w.y, (float)v1.y, of[1][3]);
            of[1][4] = fmaf(w.y, (float)v2.x, of[1][4]);
            of[1][5] = fmaf(w.y, (float)v2.y, of[1][5]);
            of[1][6] = fmaf(w.y, (float)v3.x, of[1][6]);
            of[1][7] = fmaf(w.y, (float)v3.y, of[1][7]);
        }
    }

    // final reductions: l over all 64 lanes; of parity halves
    #pragma unroll
    for (int r = 0; r < 2; ++r) {
        #pragma unroll
        for (int off = 32; off; off >>= 1) l[r] += __shfl_xor(l[r], off, 64);
        #pragma unroll
        for (int k = 0; k < 8; ++k) of[r][k] += __shfl_xor(of[r][k], 32, 64);
    }

    if (lane < 32) {
        #pragma unroll
        for (int r = 0; r < 2; ++r) {
            const int row = r0 + r;
            if (out_v) {              // NS == 1 direct path
                const float inv = 1.0f / l[r];    // self-loop -> l > 0
                if (bf) {
                    u16* out = (u16*)out_v;
                    ushort4 oa, ob;
                    oa.x = f2bf(of[r][0] * inv); oa.y = f2bf(of[r][1] * inv);
                    oa.z = f2bf(of[r][2] * inv); oa.w = f2bf(of[r][3] * inv);
                    ob.x = f2bf(of[r][4] * inv); ob.y = f2bf(of[r][5] * inv);
                    ob.z = f2bf(of[r][6] * inv); ob.w = f2bf(of[r][7] * inv);
                    *(ushort4*)(out + (size_t)row * NC + 8 * oc)     = oa;
                    *(ushort4*)(out + (size_t)row * NC + 8 * oc + 4) = ob;
                } else {
                    float* out = (float*)out_v;
                    *(float4*)(out + (size_t)row * NC + 8 * oc) =
                        make_float4(of[r][0] * inv, of[r][1] * inv,
                                    of[r][2] * inv, of[r][3] * inv);
                    *(float4*)(out + (size_t)row * NC + 8 * oc + 4) =
                        make_float4(of[r][4] * inv, of[r][5] * inv,
                                    of[r][6] * inv, of[r][7] * inv);
                }
            } else {                  // partial path
                float* pp = po + ((size_t)z * NNODE + row) * NC + 8 * oc;
                *(float4*)pp       = make_float4(of[r][0], of[r][1], of[r][2], of[r][3]);
                *(float4*)(pp + 4) = make_float4(of[r][4], of[r][5], of[r][6], of[r][7]);
            }
        }
    }
    if (!out_v && lane == 0) {
        #pragma unroll
        for (int r = 0; r < 2; ++r) {
            pm [(size_t)z * NNODE + r0 + r] = 0.f;   // no max tracking
            pls[(size_t)z * NNODE + r0 + r] = l[r];
        }
    }
}

// ---------------------------------------------------------------------------
// K3: merge NS partials per row (verified r14/r15, ns==8 fast path).
// ---------------------------------------------------------------------------
__global__ __launch_bounds__(256) void combine_kernel(
    const float* __restrict__ po, const float* __restrict__ pm,
    const float* __restrict__ pls, const u16* __restrict__ nodes_u16,
    int ns, void* __restrict__ out_v)
{
    const int bf  = wave_detect(nodes_u16, threadIdx.x & 63);
    const int row = blockIdx.x;
    const int c   = threadIdx.x;

    float v;
    if (ns == 8) {
        float mv[8], lv[8], ov[8];
        #pragma unroll
        for (int zz = 0; zz < 8; ++zz) {
            mv[zz] = pm [zz * NNODE + row];
            lv[zz] = pls[zz * NNODE + row];
            ov[zz] = po [(size_t)(zz * NNODE + row) * NC + c];
        }
        float mstar = mv[0];
        #pragma unroll
        for (int zz = 1; zz < 8; ++zz) mstar = fmaxf(mstar, mv[zz]);
        float acc = 0.f, lsum = 0.f;
        #pragma unroll
        for (int zz = 0; zz < 8; ++zz) {
            const float wz = __expf(mv[zz] - mstar);
            lsum = fmaf(lv[zz], wz, lsum);
            acc  = fmaf(ov[zz], wz, acc);
        }
        v = acc / lsum;
    } else {
        float mstar = -1e30f;
        for (int zz = 0; zz < ns; ++zz)
            mstar = fmaxf(mstar, pm[zz * NNODE + row]);
        float acc = 0.f, lsum = 0.f;
        for (int zz = 0; zz < ns; ++zz) {
            const float wz = __expf(pm[zz * NNODE + row] - mstar);
            lsum = fmaf(pls[zz * NNODE + row], wz, lsum);
            acc  = fmaf(po[(size_t)(zz * NNODE + row) * NC + c], wz, acc);
        }
        v = acc / lsum;
    }
    if (bf) ((u16*)out_v)[row * NC + c] = f2bf(v);
    else    ((float*)out_v)[row * NC + c] = v;
}

extern "C" void kernel_launch(void* const* d_in, const int* in_sizes, int n_in,
                              void* d_out, int out_size, void* d_ws, size_t ws_size,
                              hipStream_t stream)
{
    const u16* nodes_u16 = (const u16*)d_in[0];
    const int* adj       = (const int*)d_in[1];

    char*  wsb   = (char*)d_ws;
    u16*   gsh   = (u16*)wsb;
    u16*   gth   = gsh + (size_t)NNODE * NC;
    float* sgt06 = (float*)(wsb + 2ull * NNODE * NC * sizeof(u16));

    lin_kernel<<<dim3(8, 64), 256, 0, stream>>>(d_in[0], d_in[2], d_in[3],
                                                d_in[4], d_in[5], gsh, gth);
    sdot_kernel<<<256, 256, 0, stream>>>(gth, d_in[6], nodes_u16, sgt06);

    const size_t base = 2ull * NNODE * NC * sizeof(u16) + NNODE * sizeof(float);
    const size_t per  = 4ull * NNODE * NC + 8ull * NNODE;  // bytes per NS unit
    int NS = 0;
    if      (ws_size >= base + 8 * per) NS = 8;
    else if (ws_size >= base + 4 * per) NS = 4;
    else if (ws_size >= base + 2 * per) NS = 2;

    if (NS) {
        float* po  = (float*)(wsb + base);
        float* pm  = po + (size_t)NS * NNODE * NC;
        float* pls = pm + (size_t)NS * NNODE;
        fused_kernel<<<dim3(64, NS), 512, 0, stream>>>(
            gsh, gth, d_in[6], adj, nodes_u16, sgt06, NNODE / NS,
            po, pm, pls, nullptr);
        combine_kernel<<<NNODE, 256, 0, stream>>>(po, pm, pls, nodes_u16, NS, d_out);
    } else {
        fused_kernel<<<dim3(64, 1), 512, 0, stream>>>(
            gsh, gth, d_in[6], adj, nodes_u16, sgt06, NNODE,
            nullptr, nullptr, nullptr, d_out);
    }
}

// Round 19
// 60.529 us; speedup vs baseline: 1.1949x; 1.1949x over previous
//
#include <hip/hip_runtime.h>

// GATv2 layer, N=1024 nodes, C=256 channels. Flash-fused, dtype-adaptive.
// v16 = revert to v13 (best verified band: r14/r15/r16 totals 60.4-61.3us;
// fused 42.8us, VGPR 108, no spill) + packed float2 p-buffer (both rows'
// p in one b64 read; piece verified correct inside r18's passing kernel).
// r18 lesson recorded: L2-direct gt reads cost +31% vs LDS staging --
// the staging is load-bearing; barriers were not the bottleneck.
//
// ws layout (bytes):
//   [0,   512K)    gsh  g_src as f16 [1024][256]
//   [512K, 1M)     gth  g_tgt as f16 [1024][256]
//   [1M,  1M+4K)   sgt06: 0.6 * dot(a, g_tgt[j]) per j, f32
//   [+,  +NS*1M)   po   partial O f32 [NS][1024][256]
//   next NS*4K     pm   partial max per (z,row)  (always 0)
//   next NS*4K     pls  partial denom per (z,row)

typedef unsigned short u16;
typedef unsigned int   u32;
typedef _Float16 h2 __attribute__((ext_vector_type(2)));

#define NNODE 1024
#define NC    256
#define NEG   0.2f
#define BUFU  8192        // u32 per gt buffer (64 rows x 128)

__device__ __forceinline__ float bf2f(u16 h) {
    u32 u = ((u32)h) << 16;
    return __builtin_bit_cast(float, u);
}
__device__ __forceinline__ u16 f2bf(float f) {
    u32 u = __builtin_bit_cast(u32, f);
    u32 r = (u + 0x7FFFu + ((u >> 16) & 1u)) >> 16;   // RNE
    return (u16)r;
}
__device__ __forceinline__ u16 f2h(float f) {
    _Float16 h = (_Float16)f;                         // RNE
    return __builtin_bit_cast(u16, h);
}
__device__ __forceinline__ h2 bch(u32 u) { return __builtin_bit_cast(h2, u); }
__device__ __forceinline__ h2 habs2(h2 y) {           // |y| packed: 1 v_and
    u32 u = __builtin_bit_cast(u32, y) & 0x7FFF7FFFu;
    return __builtin_bit_cast(h2, u);
}
__device__ __forceinline__ float dot2(h2 a, h2 b, float acc) {
#if __has_builtin(__builtin_amdgcn_fdot2)
    return __builtin_amdgcn_fdot2(a, b, acc, false);
#else
    acc = fmaf((float)a.x, (float)b.x, acc);
    return fmaf((float)a.y, (float)b.y, acc);
#endif
}

// per-wave dtype probe (uniform; verified rounds 2..18).
__device__ __forceinline__ int wave_detect(const u16* __restrict__ nodes, int lane)
{
    ushort4 v = *(const ushort4*)(nodes + lane * 4);
    const u16 h[4] = {v.x, v.y, v.z, v.w};
    int cnt = 0;
    #pragma unroll
    for (int q = 0; q < 4; ++q) {
        int e = (h[q] >> 7) & 0xFF;
        cnt += (e >= 132 || (e >= 1 && e <= 90)) ? 1 : 0;
    }
    #pragma unroll
    for (int off = 32; off; off >>= 1) cnt += __shfl_xor(cnt, off, 64);
    return (cnt >= 64) ? 0 : 1;
}

// LDS swizzle: 16B column-group XORed with row (verified rounds 7..17).
__device__ __forceinline__ int swz(int grp, int row) { return grp ^ (row & 31); }

// ---------------------------------------------------------------------------
// K1: g = nodes @ W^T + b, output packed f16 (gsh / gth). r15/16-verified.
// 16-row i-tiles, grid (8, 64) = 512 blocks, 256 threads.
// ---------------------------------------------------------------------------
__global__ __launch_bounds__(256) void lin_kernel(
    const void* __restrict__ nodes_v,
    const void* __restrict__ Wsrc_v, const void* __restrict__ bsrc_v,
    const void* __restrict__ Wtgt_v, const void* __restrict__ btgt_v,
    u16* __restrict__ gsh, u16* __restrict__ gth)
{
    __shared__ float nT[64][17];   // [k][i], 16 rows
    __shared__ float wT[64][68];   // [k][c]

    const int t  = threadIdx.x;
    const int bf = wave_detect((const u16*)nodes_v, t & 63);
    const int ct = blockIdx.x;
    const int it = blockIdx.y;
    const int i0 = it * 16;
    const bool is_src = (ct < 4);
    const int c0 = (is_src ? ct : ct - 4) * 64;
    const void* __restrict__ Wv = is_src ? Wsrc_v : Wtgt_v;
    const void* __restrict__ bv = is_src ? bsrc_v : btgt_v;
    u16* __restrict__ g         = is_src ? gsh : gth;

    const int tc = t & 15, ti = t >> 4;
    float acc[4] = {};

    for (int k0 = 0; k0 < NC; k0 += 64) {
        __syncthreads();
        {   // stage nodes tile [16 i][64 k] -> nT[k][i]
            int kg = t & 15, ii = t >> 4;
            float vals[4];
            if (bf) {
                ushort4 v = *(const ushort4*)((const u16*)nodes_v + (i0 + ii) * NC + k0 + kg * 4);
                vals[0] = bf2f(v.x); vals[1] = bf2f(v.y);
                vals[2] = bf2f(v.z); vals[3] = bf2f(v.w);
            } else {
                const float* nf = (const float*)nodes_v;
                float4 v = *(const float4*)(nf + (i0 + ii) * NC + k0 + kg * 4);
                vals[0] = v.x; vals[1] = v.y; vals[2] = v.z; vals[3] = v.w;
            }
            #pragma unroll
            for (int q = 0; q < 4; ++q) nT[kg * 4 + q][ii] = vals[q];
        }
        {   // stage W tile [64 c][64 k] -> wT[k][c]
            int cc = t & 63, kg = t >> 6;
            float vals[16];
            if (bf) {
                const u16* W = (const u16*)Wv;
                uint4 v0 = *(const uint4*)(W + (c0 + cc) * NC + k0 + kg * 16);
                uint4 v1 = *(const uint4*)(W + (c0 + cc) * NC + k0 + kg * 16 + 8);
                const u16* p0 = (const u16*)&v0;
                const u16* p1 = (const u16*)&v1;
                #pragma unroll
                for (int q = 0; q < 8; ++q) { vals[q] = bf2f(p0[q]); vals[8 + q] = bf2f(p1[q]); }
            } else {
                const float* W = (const float*)Wv;
                #pragma unroll
                for (int h = 0; h < 4; ++h) {
                    float4 v = *(const float4*)(W + (c0 + cc) * NC + k0 + kg * 16 + 4 * h);
                    vals[4 * h + 0] = v.x; vals[4 * h + 1] = v.y;
                    vals[4 * h + 2] = v.z; vals[4 * h + 3] = v.w;
                }
            }
            #pragma unroll
            for (int q = 0; q < 16; ++q) wT[kg * 16 + q][cc] = vals[q];
        }
        __syncthreads();
        #pragma unroll 8
        for (int kk = 0; kk < 64; ++kk) {
            float  a  = nT[kk][ti];
            float4 bv4 = *(const float4*)&wT[kk][4 * tc];
            acc[0] = fmaf(a, bv4.x, acc[0]);
            acc[1] = fmaf(a, bv4.y, acc[1]);
            acc[2] = fmaf(a, bv4.z, acc[2]);
            acc[3] = fmaf(a, bv4.w, acc[3]);
        }
    }

    float bb[4];
    #pragma unroll
    for (int q = 0; q < 4; ++q)
        bb[q] = bf ? bf2f(((const u16*)bv)[c0 + 4 * tc + q])
                   : ((const float*)bv)[c0 + 4 * tc + q];
    const int irow = i0 + ti;
    ushort4 ov;
    ov.x = f2h(acc[0] + bb[0]);
    ov.y = f2h(acc[1] + bb[1]);
    ov.z = f2h(acc[2] + bb[2]);
    ov.w = f2h(acc[3] + bb[3]);
    *(ushort4*)(g + (size_t)irow * NC + c0 + 4 * tc) = ov;
}

// ---------------------------------------------------------------------------
// K1b: sgt06[j] = 0.6 * sum_c a_c * g_tgt[j][c]  (verified round 8).
// grid 256 x 256; wave = row.
// ---------------------------------------------------------------------------
__global__ __launch_bounds__(256) void sdot_kernel(
    const u16* __restrict__ gth, const void* __restrict__ aw_v,
    const u16* __restrict__ nodes_u16, float* __restrict__ sgt06)
{
    const int t    = threadIdx.x;
    const int lane = t & 63;
    const int bf   = wave_detect(nodes_u16, lane);
    const int row  = blockIdx.x * 4 + (t >> 6);

    float a0, a1, a2, a3;
    if (bf) {
        ushort4 a4 = *(const ushort4*)((const u16*)aw_v + lane * 4);
        a0 = bf2f(a4.x); a1 = bf2f(a4.y); a2 = bf2f(a4.z); a3 = bf2f(a4.w);
    } else {
        float4 a4 = *(const float4*)((const float*)aw_v + lane * 4);
        a0 = a4.x; a1 = a4.y; a2 = a4.z; a3 = a4.w;
    }
    ushort4 gv = *(const ushort4*)(gth + (size_t)row * NC + lane * 4);
    float s = a0 * (float)__builtin_bit_cast(_Float16, gv.x)
            + a1 * (float)__builtin_bit_cast(_Float16, gv.y)
            + a2 * (float)__builtin_bit_cast(_Float16, gv.z)
            + a3 * (float)__builtin_bit_cast(_Float16, gv.w);
    #pragma unroll
    for (int off = 32; off; off >>= 1) s += __shfl_xor(s, off, 64);
    if (lane == 0) sgt06[row] = 0.6f * s;
}

// ---------------------------------------------------------------------------
// K2: fused score + softmax (no max-subtraction) + PV. r14-verified body
// (42.8us); p buffer packed as float2 (one b64 read serves both rows).
// 512 threads, 8 waves, 2 rows/wave; async double-buffered gt staging
// (swizzle on global src, lane-linear DMA dest).
// ---------------------------------------------------------------------------
__global__ __launch_bounds__(512, 2) void fused_kernel(
    const u16* __restrict__ gsh, const u16* __restrict__ gth,
    const void* __restrict__ aw_v, const int* __restrict__ adj,
    const u16* __restrict__ nodes_u16, const float* __restrict__ sgt06,
    int jcnt, float* __restrict__ po, float* __restrict__ pm,
    float* __restrict__ pls, void* __restrict__ out_v)
{
    __shared__ u32    gt32[2 * BUFU];  // 2 x 32 KB swizzled-content buffers
    __shared__ u32    a32[128];        // 0.4*a as f16x2
    __shared__ float2 p2[8][64];       // per-wave packed (p_row0, p_row1)

    const int t    = threadIdx.x;
    const int i    = t >> 6;          // wave id 0..7; rows 2i, 2i+1
    const int lane = t & 63;
    const int bf   = wave_detect(nodes_u16, lane);
    const int r0   = blockIdx.x * 16 + 2 * i;
    const int z    = blockIdx.y;
    const int jbase = z * jcnt;
    const int nt   = jcnt >> 6;       // 64-j tiles
    const int jl = lane & 15, q  = lane >> 4;   // score layout
    const int oc = lane & 31, hh = lane >> 5;   // PV layout

    auto stage_tile = [&](int bufIdx, int j0s) {
        #pragma unroll
        for (int c = 0; c < 4; ++c) {
            const int row = 16 * c + 2 * i + (lane >> 5);
            const int g   = lane & 31;
            const u16* gp = gth + (size_t)(j0s + row) * NC + (g ^ (row & 31)) * 8;
            u32* lp = gt32 + bufIdx * BUFU + row * 128 + g * 4;
            __builtin_amdgcn_global_load_lds(
                (const __attribute__((address_space(1))) void*)gp,
                (__attribute__((address_space(3))) void*)lp, 16, 0, 0);
        }
    };

    if (t < 128) {                    // stage 0.4*a as f16x2 (flag-converted)
        float a0, a1;
        if (bf) { a0 = bf2f(((const u16*)aw_v)[2 * t]); a1 = bf2f(((const u16*)aw_v)[2 * t + 1]); }
        else    { a0 = ((const float*)aw_v)[2 * t];     a1 = ((const float*)aw_v)[2 * t + 1]; }
        h2 av; av.x = (_Float16)(0.4f * a0); av.y = (_Float16)(0.4f * a1);
        a32[t] = __builtin_bit_cast(u32, av);
    }

    // both rows' g_src quarter (64 ch each) into registers: 2 x 32 x h2
    u32 gsr[2][32];
    #pragma unroll
    for (int r = 0; r < 2; ++r) {
        const u16* src = gsh + (size_t)(r0 + r) * NC + q * 64;
        #pragma unroll
        for (int k = 0; k < 8; ++k) {
            uint4 gv = *(const uint4*)(src + 8 * k);
            gsr[r][4 * k + 0] = gv.x; gsr[r][4 * k + 1] = gv.y;
            gsr[r][4 * k + 2] = gv.z; gsr[r][4 * k + 3] = gv.w;
        }
    }

    stage_tile(0, jbase);             // prologue: fill buffer 0
    __syncthreads();                  // drains DMA (vmcnt) + a32 visible

    // Sgs06[r] = 1.5 * dot(0.4a, gsr[r]) reduced over the wave
    float Sgs06[2];
    #pragma unroll
    for (int r = 0; r < 2; ++r) {
        float sg = 0.f;
        #pragma unroll
        for (int k = 0; k < 8; ++k) {
            uint4 a4 = *(const uint4*)&a32[q * 32 + 4 * k];
            sg = dot2(bch(a4.x), bch(gsr[r][4 * k + 0]), sg);
            sg = dot2(bch(a4.y), bch(gsr[r][4 * k + 1]), sg);
            sg = dot2(bch(a4.z), bch(gsr[r][4 * k + 2]), sg);
            sg = dot2(bch(a4.w), bch(gsr[r][4 * k + 3]), sg);
        }
        sg += __shfl_xor(sg, 16, 64);
        sg += __shfl_xor(sg, 32, 64);
        Sgs06[r] = 1.5f * sg;
    }

    float l[2] = {0.f, 0.f};          // per-lane partial sums
    float of[2][8] = {};              // [row][ch 8*oc..8*oc+7] (j-parity hh)

    for (int t2 = 0; t2 < nt; ++t2) {
        const int bb = (t2 & 1) * BUFU;
        const int j0 = jbase + t2 * 64;
        if (t2 + 1 < nt) stage_tile((t2 + 1) & 1, j0 + 64);  // async prefetch

        const float sgtj = sgt06[j0 + lane];

        // ---- score abs-part: each gt b128 feeds BOTH rows ----
        float spv[2][4] = {};
        #pragma unroll
        for (int k = 0; k < 8; ++k) {
            uint4 a4 = *(const uint4*)&a32[q * 32 + 4 * k];
            h2 a0 = bch(a4.x), a1 = bch(a4.y), a2 = bch(a4.z), a3 = bch(a4.w);
            #pragma unroll
            for (int p = 0; p < 4; ++p) {
                const int rowp = 16 * p + jl;
                uint4 g4 = *(const uint4*)&gt32[bb + rowp * 128 + swz(q * 8 + k, rowp) * 4];
                h2 t0 = bch(g4.x), t1 = bch(g4.y), t2v = bch(g4.z), t3 = bch(g4.w);
                #pragma unroll
                for (int r = 0; r < 2; ++r) {
                    spv[r][p] = dot2(a0, habs2(bch(gsr[r][4 * k + 0]) + t0), spv[r][p]);
                    spv[r][p] = dot2(a1, habs2(bch(gsr[r][4 * k + 1]) + t1), spv[r][p]);
                    spv[r][p] = dot2(a2, habs2(bch(gsr[r][4 * k + 2]) + t2v), spv[r][p]);
                    spv[r][p] = dot2(a3, habs2(bch(gsr[r][4 * k + 3]) + t3), spv[r][p]);
                }
            }
        }
        #pragma unroll
        for (int r = 0; r < 2; ++r)
            #pragma unroll
            for (int p = 0; p < 4; ++p) {   // reduce over q (lane bits 4,5)
                spv[r][p] += __shfl_xor(spv[r][p], 16, 64);
                spv[r][p] += __shfl_xor(spv[r][p], 32, 64);
            }

        // ---- p = exp(s) directly (verified r13); l per-lane ----
        float pr[2];
        #pragma unroll
        for (int r = 0; r < 2; ++r) {
            const float sabs = (lane < 16) ? spv[r][0] : (lane < 32) ? spv[r][1]
                             : (lane < 48) ? spv[r][2] : spv[r][3];
            const float s = sabs + Sgs06[r] + sgtj;
            const int valid = adj[(size_t)(r0 + r) * NNODE + j0 + lane];
            pr[r] = valid ? __expf(s) : 0.f;
            l[r] += pr[r];
        }
        p2[i][lane] = make_float2(pr[0], pr[1]);   // wave-local, one b64

        // ---- PV: per 2 j one b128 (8 ch) + one packed p read ----
        #pragma unroll 4
        for (int jp = 0; jp < 32; ++jp) {
            const int j = 2 * jp + hh;
            const float2 w = p2[i][j];
            uint4 g4 = *(const uint4*)&gt32[bb + j * 128 + swz(oc, j) * 4];
            h2 v0 = bch(g4.x), v1 = bch(g4.y), v2 = bch(g4.z), v3 = bch(g4.w);
            of[0][0] = fmaf(w.x, (float)v0.x, of[0][0]);
            of[0][1] = fmaf(w.x, (float)v0.y, of[0][1]);
            of[0][2] = fmaf(w.x, (float)v1.x, of[0][2]);
            of[0][3] = fmaf(w.x, (float)v1.y, of[0][3]);
            of[0][4] = fmaf(w.x, (float)v2.x, of[0][4]);
            of[0][5] = fmaf(w.x, (float)v2.y, of[0][5]);
            of[0][6] = fmaf(w.x, (float)v3.x, of[0][6]);
            of[0][7] = fmaf(w.x, (float)v3.y, of[0][7]);
            of[1][0] = fmaf(w.y, (float)v0.x, of[1][0]);
            of[1][1] = fmaf(w.y, (float)v0.y, of[1][1]);
            of[1][2] = fmaf(w.y, (float)v1.x, of[1][2]);
            of[1][3] = fmaf(w.y, (float)v1.y, of[1][3]);
            of[1][4] = fmaf(w.y, (float)v2.x, of[1][4]);
            of[1][5] = fmaf(w.y, (float)v2.y, of[1][5]);
            of[1][6] = fmaf(w.y, (float)v3.x, of[1][6]);
            of[1][7] = fmaf(w.y, (float)v3.y, of[1][7]);
        }

        __syncthreads();              // compute done + next DMA drained
    }

    // final reductions: l over all 64 lanes; of parity halves
    #pragma unroll
    for (int r = 0; r < 2; ++r) {
        #pragma unroll
        for (int off = 32; off; off >>= 1) l[r] += __shfl_xor(l[r], off, 64);
        #pragma unroll
        for (int k = 0; k < 8; ++k) of[r][k] += __shfl_xor(of[r][k], 32, 64);
    }

    if (lane < 32) {
        #pragma unroll
        for (int r = 0; r < 2; ++r) {
            const int row = r0 + r;
            if (out_v) {              // NS == 1 direct path
                const float inv = 1.0f / l[r];    // self-loop -> l > 0
                if (bf) {
                    u16* out = (u16*)out_v;
                    ushort4 oa, ob;
                    oa.x = f2bf(of[r][0] * inv); oa.y = f2bf(of[r][1] * inv);
                    oa.z = f2bf(of[r][2] * inv); oa.w = f2bf(of[r][3] * inv);
                    ob.x = f2bf(of[r][4] * inv); ob.y = f2bf(of[r][5] * inv);
                    ob.z = f2bf(of[r][6] * inv); ob.w = f2bf(of[r][7] * inv);
                    *(ushort4*)(out + (size_t)row * NC + 8 * oc)     = oa;
                    *(ushort4*)(out + (size_t)row * NC + 8 * oc + 4) = ob;
                } else {
                    float* out = (float*)out_v;
                    *(float4*)(out + (size_t)row * NC + 8 * oc) =
                        make_float4(of[r][0] * inv, of[r][1] * inv,
                                    of[r][2] * inv, of[r][3] * inv);
                    *(float4*)(out + (size_t)row * NC + 8 * oc + 4) =
                        make_float4(of[r][4] * inv, of[r][5] * inv,
                                    of[r][6] * inv, of[r][7] * inv);
                }
            } else {                  // partial path
                float* pp = po + ((size_t)z * NNODE + row) * NC + 8 * oc;
                *(float4*)pp       = make_float4(of[r][0], of[r][1], of[r][2], of[r][3]);
                *(float4*)(pp + 4) = make_float4(of[r][4], of[r][5], of[r][6], of[r][7]);
            }
        }
    }
    if (!out_v && lane == 0) {
        #pragma unroll
        for (int r = 0; r < 2; ++r) {
            pm [(size_t)z * NNODE + r0 + r] = 0.f;   // no max tracking
            pls[(size_t)z * NNODE + r0 + r] = l[r];
        }
    }
}

// ---------------------------------------------------------------------------
// K3: merge NS partials per row (verified r14/r15, ns==8 fast path).
// ---------------------------------------------------------------------------
__global__ __launch_bounds__(256) void combine_kernel(
    const float* __restrict__ po, const float* __restrict__ pm,
    const float* __restrict__ pls, const u16* __restrict__ nodes_u16,
    int ns, void* __restrict__ out_v)
{
    const int bf  = wave_detect(nodes_u16, threadIdx.x & 63);
    const int row = blockIdx.x;
    const int c   = threadIdx.x;

    float v;
    if (ns == 8) {
        float mv[8], lv[8], ov[8];
        #pragma unroll
        for (int zz = 0; zz < 8; ++zz) {
            mv[zz] = pm [zz * NNODE + row];
            lv[zz] = pls[zz * NNODE + row];
            ov[zz] = po [(size_t)(zz * NNODE + row) * NC + c];
        }
        float mstar = mv[0];
        #pragma unroll
        for (int zz = 1; zz < 8; ++zz) mstar = fmaxf(mstar, mv[zz]);
        float acc = 0.f, lsum = 0.f;
        #pragma unroll
        for (int zz = 0; zz < 8; ++zz) {
            const float wz = __expf(mv[zz] - mstar);
            lsum = fmaf(lv[zz], wz, lsum);
            acc  = fmaf(ov[zz], wz, acc);
        }
        v = acc / lsum;
    } else {
        float mstar = -1e30f;
        for (int zz = 0; zz < ns; ++zz)
            mstar = fmaxf(mstar, pm[zz * NNODE + row]);
        float acc = 0.f, lsum = 0.f;
        for (int zz = 0; zz < ns; ++zz) {
            const float wz = __expf(pm[zz * NNODE + row] - mstar);
            lsum = fmaf(pls[zz * NNODE + row], wz, lsum);
            acc  = fmaf(po[(size_t)(zz * NNODE + row) * NC + c], wz, acc);
        }
        v = acc / lsum;
    }
    if (bf) ((u16*)out_v)[row * NC + c] = f2bf(v);
    else    ((float*)out_v)[row * NC + c] = v;
}

extern "C" void kernel_launch(void* const* d_in, const int* in_sizes, int n_in,
                              void* d_out, int out_size, void* d_ws, size_t ws_size,
                              hipStream_t stream)
{
    const u16* nodes_u16 = (const u16*)d_in[0];
    const int* adj       = (const int*)d_in[1];

    char*  wsb   = (char*)d_ws;
    u16*   gsh   = (u16*)wsb;
    u16*   gth   = gsh + (size_t)NNODE * NC;
    float* sgt06 = (float*)(wsb + 2ull * NNODE * NC * sizeof(u16));

    lin_kernel<<<dim3(8, 64), 256, 0, stream>>>(d_in[0], d_in[2], d_in[3],
                                                d_in[4], d_in[5], gsh, gth);
    sdot_kernel<<<256, 256, 0, stream>>>(gth, d_in[6], nodes_u16, sgt06);

    const size_t base = 2ull * NNODE * NC * sizeof(u16) + NNODE * sizeof(float);
    const size_t per  = 4ull * NNODE * NC + 8ull * NNODE;  // bytes per NS unit
    int NS = 0;
    if      (ws_size >= base + 8 * per) NS = 8;
    else if (ws_size >= base + 4 * per) NS = 4;
    else if (ws_size >= base + 2 * per) NS = 2;

    if (NS) {
        float* po  = (float*)(wsb + base);
        float* pm  = po + (size_t)NS * NNODE * NC;
        float* pls = pm + (size_t)NS * NNODE;
        fused_kernel<<<dim3(64, NS), 512, 0, stream>>>(
            gsh, gth, d_in[6], adj, nodes_u16, sgt06, NNODE / NS,
            po, pm, pls, nullptr);
        combine_kernel<<<NNODE, 256, 0, stream>>>(po, pm, pls, nodes_u16, NS, d_out);
    } else {
        fused_kernel<<<dim3(64, 1), 512, 0, stream>>>(
            gsh, gth, d_in[6], adj, nodes_u16, sgt06, NNODE,
            nullptr, nullptr, nullptr, d_out);
    }
}